// Round 7
// baseline (159.012 us; speedup 1.0000x reference)
//
#include <hip/hip_runtime.h>
#include <math.h>

#define G   50
#define T   24
#define B   128
#define NLP (B * T)
#define SZ  (B * G * T)   // 153600 elements per (B,G,T) output

// d_out layout (floats, concatenated in return order):
//   [0,      SZ)        P_DA   (B,G,T)
//   [SZ,     2SZ)       R_up
//   [2SZ,    3SZ)       R_dn
//   [3SZ,    3SZ+B)     obj    (B,)
//   [3SZ+B,  4SZ+B)     Cost_DA

// Full 64-lane sum of three values -> SGPRs (readlane 63), fully fused DPP.
// Chains interleaved: every DPP/readlane source has >=2 intervening instrs
// (VALU-write -> DPP-read needs 2 wait states). s_nop 1 guards entry; s_nop 3
// guards the SGPR-write -> VALU-read hazard after the final readlane.
__device__ __forceinline__ void wave_sum3_sgpr(float a, float b, float c,
                                               float& sa, float& sb, float& sc) {
    float ra, rb, rc;
    asm("s_nop 1\n\t"
        "v_add_f32_dpp %3, %3, %3 row_ror:1 row_mask:0xf bank_mask:0xf\n\t"
        "v_add_f32_dpp %4, %4, %4 row_ror:1 row_mask:0xf bank_mask:0xf\n\t"
        "v_add_f32_dpp %5, %5, %5 row_ror:1 row_mask:0xf bank_mask:0xf\n\t"
        "v_add_f32_dpp %3, %3, %3 row_ror:2 row_mask:0xf bank_mask:0xf\n\t"
        "v_add_f32_dpp %4, %4, %4 row_ror:2 row_mask:0xf bank_mask:0xf\n\t"
        "v_add_f32_dpp %5, %5, %5 row_ror:2 row_mask:0xf bank_mask:0xf\n\t"
        "v_add_f32_dpp %3, %3, %3 row_ror:4 row_mask:0xf bank_mask:0xf\n\t"
        "v_add_f32_dpp %4, %4, %4 row_ror:4 row_mask:0xf bank_mask:0xf\n\t"
        "v_add_f32_dpp %5, %5, %5 row_ror:4 row_mask:0xf bank_mask:0xf\n\t"
        "v_add_f32_dpp %3, %3, %3 row_ror:8 row_mask:0xf bank_mask:0xf\n\t"
        "v_add_f32_dpp %4, %4, %4 row_ror:8 row_mask:0xf bank_mask:0xf\n\t"
        "v_add_f32_dpp %5, %5, %5 row_ror:8 row_mask:0xf bank_mask:0xf\n\t"
        "v_add_f32_dpp %3, %3, %3 row_bcast:15 row_mask:0xa bank_mask:0xf\n\t"
        "v_add_f32_dpp %4, %4, %4 row_bcast:15 row_mask:0xa bank_mask:0xf\n\t"
        "v_add_f32_dpp %5, %5, %5 row_bcast:15 row_mask:0xa bank_mask:0xf\n\t"
        "v_add_f32_dpp %3, %3, %3 row_bcast:31 row_mask:0xc bank_mask:0xf\n\t"
        "v_add_f32_dpp %4, %4, %4 row_bcast:31 row_mask:0xc bank_mask:0xf\n\t"
        "v_add_f32_dpp %5, %5, %5 row_bcast:31 row_mask:0xc bank_mask:0xf\n\t"
        "v_readlane_b32 %0, %3, 63\n\t"
        "v_readlane_b32 %1, %4, 63\n\t"
        "v_readlane_b32 %2, %5, 63\n\t"
        "s_nop 3"
        : "=s"(ra), "=s"(rb), "=s"(rc), "+v"(a), "+v"(b), "+v"(c));
    sa = ra; sb = rb; sc = rc;
}

// One 64-lane wave per LP; lane = generator (lanes >= 50 are sentinel-masked).
// 256-thread blocks carry 4 independent waves/LPs.
__global__ __launch_bounds__(256)
void pdhg_lp_kernel(const float* __restrict__ forecast,
                    const float* __restrict__ pmin,
                    const float* __restrict__ pmax,
                    const float* __restrict__ bcost,
                    const float* __restrict__ ccost,
                    const int*   __restrict__ n_iters_p,
                    float* __restrict__ out,
                    float* __restrict__ ws_partial,   // NLP floats (or null)
                    float tau)
{
    const int lane = threadIdx.x & 63;
    const int lp   = blockIdx.x * 4 + (threadIdx.x >> 6);
    const int b    = lp / T;
    const int t    = lp - b * T;
    const int n_iters = n_iters_p[0];

    const bool  valid = (lane < G);
    const int   gl  = valid ? lane : (G - 1);
    const float bj  = bcost[gl];
    const float cj  = valid ? ccost[gl] : 0.f;
    const float f   = forecast[lp];          // wave-uniform

    const float ts  = tau * tau;             // sigma == tau
    const float BIG = 1e30f;                 // sentinel: clamps invalid lanes to 0

    // pre-multiplied constants (per-lane VGPRs)
    const float tcP   = valid ? tau * bj          : BIG;
    const float tcRu  = valid ? tau * 0.05f * bj  : BIG;
    const float tcRd  = valid ? tau * 0.02f * bj  : BIG;
    const float tspmx = valid ? ts * pmax[gl]     : 0.f;
    const float tspmn = valid ? ts * pmin[gl]     : 0.f;
    const float tsf   = ts * f;
    const float tsreq = ts * 0.02f * f;      // REQ_UP_RATIO == REQ_DN_RATIO

    // state: primal P,Ru,Rd; duals z1,z3 (>=0), negated nz2,nz4 (<=0);
    // wave-uniform z0,zru,zrd kept replicated in VGPRs.
    float P = 0.f, Ru = 0.f, Rd = 0.f;
    float z1 = 0.f, nz2 = 0.f, z3 = 0.f, nz4 = 0.f;
    float z0 = 0.f, zru = 0.f, zrd = 0.f;

    for (int it = 0; it < n_iters; ++it) {
        // ---- x-update: x_new = max(x - (tau*c + tau*K^T y), 0) ----
        float gP  = ((z0 + z1) + (nz2 + z3)) + nz4;   // K^T y for P (scaled)
        float Pn  = fmaxf(P  - (tcP + gP),        0.f);
        float Run = fmaxf(((Ru - z1)  + zru) - tcRu, 0.f);
        float Rdn = fmaxf(((Rd + nz2) + zrd) - tcRd, 0.f);

        // overrelaxation: x_bar = 2*x_new - x_old
        float Pb  = fmaf(2.f, Pn,  -P);
        float Rub = fmaf(2.f, Run, -Ru);
        float Rdb = fmaf(2.f, Rdn, -Rd);
        P = Pn; Ru = Run; Rd = Rdn;

        // ---- wave sums over generators -> SGPRs ----
        float sP, sRu, sRd;
        wave_sum3_sgpr(Pb, Rub, Rdb, sP, sRu, sRd);

        // ---- z-update: z += tau*sigma*(K x_bar - q), clamp ----
        z1  = fmaxf(fmaf(ts, Pb + Rub, z1)  - tspmx, 0.f);   // P+Ru <= pmax
        nz2 = fminf(fmaf(ts, Pb - Rdb, nz2) - tspmn, 0.f);   // -(-P+Rd <= -pmin)
        z3  = fmaxf(fmaf(ts, Pb, z3)  - tspmx, 0.f);         // P <= pmax
        nz4 = fminf(fmaf(ts, Pb, nz4) - tspmn, 0.f);         // -(-P <= -pmin)
        z0  = fmaf(ts, sP, z0) - tsf;                        // equality row
        zru = fmaxf(fmaf(-ts, sRu, zru + tsreq), 0.f);       // -sum Ru <= -req
        zrd = fmaxf(fmaf(-ts, sRd, zrd + tsreq), 0.f);       // -sum Rd <= -req
    }

    const float cost = bj * P + cj;
    if (valid) {
        const int base = b * (G * T) + lane * T + t;   // (B,G,T) index
        out[base]               = P;
        out[SZ + base]          = Ru;
        out[2 * SZ + base]      = Rd;
        out[3 * SZ + B + base]  = cost;
    }

    if (ws_partial) {
        // per-(b,t) objective partial (invalid lanes: P=Ru=Rd=0, cj=0 -> 0)
        float lo = cost + 0.05f * bj * Ru + 0.02f * bj * Rd;
        float tot, d1, d2;
        wave_sum3_sgpr(lo, 0.f, 0.f, tot, d1, d2);
        if (lane == 0) ws_partial[lp] = tot;
    }
}

// obj[b] = sum_t ws_partial[b*T + t]   (deterministic, tiny)
__global__ __launch_bounds__(64)
void obj_final_kernel(const float* __restrict__ ws_partial, float* __restrict__ out)
{
    const int b = blockIdx.x * 64 + threadIdx.x;
    if (b < B) {
        float s = 0.f;
        #pragma unroll
        for (int t = 0; t < T; ++t) s += ws_partial[b * T + t];
        out[3 * SZ + b] = s;
    }
}

// Fallback (ws too small): recompute obj from outputs, one block per b
__global__ __launch_bounds__(256)
void obj_kernel(const float* __restrict__ bcost, float* __restrict__ out)
{
    const int b = blockIdx.x;
    const float* Ru = out + SZ     + (size_t)b * (G * T);
    const float* Rd = out + 2 * SZ + (size_t)b * (G * T);
    const float* C  = out + 3 * SZ + B + (size_t)b * (G * T);

    float s = 0.f;
    for (int i = threadIdx.x; i < G * T; i += 256) {
        const int g = i / T;
        const float bg = bcost[g];
        s += C[i] + 0.05f * bg * Ru[i] + 0.02f * bg * Rd[i];
    }
    float tot, d1, d2;
    wave_sum3_sgpr(s, 0.f, 0.f, tot, d1, d2);
    __shared__ float sm[4];
    if ((threadIdx.x & 63) == 0) sm[threadIdx.x >> 6] = tot;
    __syncthreads();
    if (threadIdx.x == 0) out[3 * SZ + b] = (sm[0] + sm[1]) + (sm[2] + sm[3]);
}

extern "C" void kernel_launch(void* const* d_in, const int* in_sizes, int n_in,
                              void* d_out, int out_size, void* d_ws, size_t ws_size,
                              hipStream_t stream) {
    const float* forecast = (const float*)d_in[0];
    const float* pmin_p   = (const float*)d_in[1];
    const float* pmax_p   = (const float*)d_in[2];
    const float* b_p      = (const float*)d_in[3];
    const float* c_p      = (const float*)d_in[4];
    const int*   niter_p  = (const int*)  d_in[5];
    float* out = (float*)d_out;

    // ||K||_2 analytic for this fixed 0/±1 structure (G=50):
    // K^T K = [[4I+J, I, -I],[I, I+J, 0],[-I, 0, I+J]]; largest eig on the
    // ones-subspace is (105+sqrt(17))/2  ->  L = sqrt((105+sqrt(17))/2)
    const double L = sqrt((105.0 + sqrt(17.0)) * 0.5);
    const float tau = (float)(0.9 / L);   // sigma == tau

    const bool use_ws = (ws_size >= (size_t)NLP * sizeof(float));
    float* wsp = use_ws ? (float*)d_ws : nullptr;

    pdhg_lp_kernel<<<NLP / 4, 256, 0, stream>>>(forecast, pmin_p, pmax_p,
                                                b_p, c_p, niter_p, out, wsp, tau);
    if (use_ws) {
        obj_final_kernel<<<(B + 63) / 64, 64, 0, stream>>>(wsp, out);
    } else {
        obj_kernel<<<B, 256, 0, stream>>>(b_p, out);
    }
}

// Round 8
// 158.019 us; speedup vs baseline: 1.0063x; 1.0063x over previous
//
#include <hip/hip_runtime.h>
#include <math.h>

#define G   50
#define T   24
#define B   128
#define NLP (B * T)
#define SZ  (B * G * T)   // 153600 elements per (B,G,T) output

// d_out layout (floats, concatenated in return order):
//   [0,      SZ)        P_DA   (B,G,T)
//   [SZ,     2SZ)       R_up
//   [2SZ,    3SZ)       R_dn
//   [3SZ,    3SZ+B)     obj    (B,)
//   [3SZ+B,  4SZ+B)     Cost_DA

// 12 fused v_add_f32_dpp row_ror (3 chains interleaved): after this every
// lane holds the sum of its 16-lane row for each value. s_nop 1 guards the
// producer->DPP-read 2-wait-state hazard at block entry; interleave covers it
// inside the block.
__device__ __forceinline__ void rowror_sum3(float& a, float& b, float& c) {
    asm("s_nop 1\n\t"
        "v_add_f32_dpp %0, %0, %0 row_ror:1 row_mask:0xf bank_mask:0xf\n\t"
        "v_add_f32_dpp %1, %1, %1 row_ror:1 row_mask:0xf bank_mask:0xf\n\t"
        "v_add_f32_dpp %2, %2, %2 row_ror:1 row_mask:0xf bank_mask:0xf\n\t"
        "v_add_f32_dpp %0, %0, %0 row_ror:2 row_mask:0xf bank_mask:0xf\n\t"
        "v_add_f32_dpp %1, %1, %1 row_ror:2 row_mask:0xf bank_mask:0xf\n\t"
        "v_add_f32_dpp %2, %2, %2 row_ror:2 row_mask:0xf bank_mask:0xf\n\t"
        "v_add_f32_dpp %0, %0, %0 row_ror:4 row_mask:0xf bank_mask:0xf\n\t"
        "v_add_f32_dpp %1, %1, %1 row_ror:4 row_mask:0xf bank_mask:0xf\n\t"
        "v_add_f32_dpp %2, %2, %2 row_ror:4 row_mask:0xf bank_mask:0xf\n\t"
        "v_add_f32_dpp %0, %0, %0 row_ror:8 row_mask:0xf bank_mask:0xf\n\t"
        "v_add_f32_dpp %1, %1, %1 row_ror:8 row_mask:0xf bank_mask:0xf\n\t"
        "v_add_f32_dpp %2, %2, %2 row_ror:8 row_mask:0xf bank_mask:0xf"
        : "+v"(a), "+v"(b), "+v"(c));
}

// lane ^ 16 within each 32-lane group (BitMode: xor=16, and=0x1F)
__device__ __forceinline__ float swz_xor16(float x) {
    return __int_as_float(__builtin_amdgcn_ds_swizzle(__float_as_int(x), 0x401F));
}

// scalar 16-lane row sum (epilogue only)
template <int CTRL>
__device__ __forceinline__ float dpp_mov(float x) {
    int r = __builtin_amdgcn_update_dpp(0, __float_as_int(x), CTRL, 0xf, 0xf, true);
    return __int_as_float(r);
}
__device__ __forceinline__ float row_sum1(float a) {
    a += dpp_mov<0x121>(a);
    a += dpp_mov<0x122>(a);
    a += dpp_mov<0x124>(a);
    a += dpp_mov<0x128>(a);
    return a;
}

// One wave per block; half h = lane>>5 (32 lanes) solves LP (2*blockIdx + h).
// Each lane owns generators g0 = lane&31 (always valid) and g1 = g0+32
// (valid iff g0 < 18). Sentinel BIG cost clamps invalid slots to exact 0.
__global__ __launch_bounds__(64)
void pdhg_lp_kernel(const float* __restrict__ forecast,
                    const float* __restrict__ pmin,
                    const float* __restrict__ pmax,
                    const float* __restrict__ bcost,
                    const float* __restrict__ ccost,
                    const int*   __restrict__ n_iters_p,
                    float* __restrict__ out,
                    float* __restrict__ ws_partial,   // NLP floats (or null)
                    float tau)
{
    const int lane = threadIdx.x;         // 0..63
    const int lh   = lane & 31;           // lane within half (= gen slot 0)
    const int half = lane >> 5;
    const int lp   = blockIdx.x * 2 + half;
    const int b    = lp / T;
    const int t    = lp - b * T;
    const int n_iters = n_iters_p[0];

    const int  g0 = lh;                   // < 32, always valid
    const int  g1 = lh + 32;              // valid iff < 50
    const bool v1 = (g1 < G);
    const int  gl1 = v1 ? g1 : (G - 1);

    const float bj0 = bcost[g0];
    const float bj1 = v1 ? bcost[gl1] : 0.f;
    const float cj0 = ccost[g0];
    const float cj1 = v1 ? ccost[gl1] : 0.f;
    const float f   = forecast[lp];       // uniform within each half

    const float ts  = tau * tau;          // sigma == tau
    const float BIG = 1e30f;              // sentinel: keeps invalid slot at 0

    // pre-multiplied constants
    const float tcP0   = tau * bj0;
    const float tcP1   = v1 ? tau * bj1         : BIG;
    const float tcRu0  = tau * 0.05f * bj0;
    const float tcRu1  = v1 ? tau * 0.05f * bj1 : BIG;
    const float tcRd0  = tau * 0.02f * bj0;
    const float tcRd1  = v1 ? tau * 0.02f * bj1 : BIG;
    const float tspmx0 = ts * pmax[g0];
    const float tspmx1 = v1 ? ts * pmax[gl1] : 0.f;
    const float tspmn0 = ts * pmin[g0];
    const float tspmn1 = v1 ? ts * pmin[gl1] : 0.f;
    const float tsf    = ts * f;
    const float tsreq  = ts * 0.02f * f;  // REQ_UP_RATIO == REQ_DN_RATIO

    // state (two generator slots per lane); duals scaled by tau, rows 3/5 negated
    float P0 = 0.f, Ru0 = 0.f, Rd0 = 0.f, P1 = 0.f, Ru1 = 0.f, Rd1 = 0.f;
    float z1_0 = 0.f, nz2_0 = 0.f, z3_0 = 0.f, nz4_0 = 0.f;
    float z1_1 = 0.f, nz2_1 = 0.f, z3_1 = 0.f, nz4_1 = 0.f;
    float z0 = 0.f, zru = 0.f, zrd = 0.f;   // half-uniform (replicated)

    for (int it = 0; it < n_iters; ++it) {
        // ---- x-update: x_new = max(x - (tau*c + tau*K^T y), 0) ----
        float gP0 = ((z0 + z1_0) + (nz2_0 + z3_0)) + nz4_0;
        float gP1 = ((z0 + z1_1) + (nz2_1 + z3_1)) + nz4_1;
        float Pn0 = fmaxf(P0 - (tcP0 + gP0), 0.f);
        float Pn1 = fmaxf(P1 - (tcP1 + gP1), 0.f);
        float Run0 = fmaxf(((Ru0 - z1_0) + zru) - tcRu0, 0.f);
        float Run1 = fmaxf(((Ru1 - z1_1) + zru) - tcRu1, 0.f);
        float Rdn0 = fmaxf(((Rd0 + nz2_0) + zrd) - tcRd0, 0.f);
        float Rdn1 = fmaxf(((Rd1 + nz2_1) + zrd) - tcRd1, 0.f);

        // overrelaxation: x_bar = 2*x_new - x_old
        float Pb0  = fmaf(2.f, Pn0,  -P0),  Pb1  = fmaf(2.f, Pn1,  -P1);
        float Rub0 = fmaf(2.f, Run0, -Ru0), Rub1 = fmaf(2.f, Run1, -Ru1);
        float Rdb0 = fmaf(2.f, Rdn0, -Rd0), Rdb1 = fmaf(2.f, Rdn1, -Rd1);
        P0 = Pn0; P1 = Pn1; Ru0 = Run0; Ru1 = Run1; Rd0 = Rdn0; Rd1 = Rdn1;

        // ---- 32-lane sums: pair-fold + row_ror DPP + xor16 swizzle fold ----
        float sP  = Pb0  + Pb1;
        float sRu = Rub0 + Rub1;
        float sRd = Rdb0 + Rdb1;
        rowror_sum3(sP, sRu, sRd);
        // issue the DS folds early; their latency hides under the z-updates
        float wP  = swz_xor16(sP);
        float wRu = swz_xor16(sRu);
        float wRd = swz_xor16(sRd);

        // ---- per-lane z-updates (independent of the sums) ----
        z1_0  = fmaxf(fmaf(ts, Pb0 + Rub0, z1_0)  - tspmx0, 0.f);
        z1_1  = fmaxf(fmaf(ts, Pb1 + Rub1, z1_1)  - tspmx1, 0.f);
        nz2_0 = fminf(fmaf(ts, Pb0 - Rdb0, nz2_0) - tspmn0, 0.f);
        nz2_1 = fminf(fmaf(ts, Pb1 - Rdb1, nz2_1) - tspmn1, 0.f);
        z3_0  = fmaxf(fmaf(ts, Pb0, z3_0)  - tspmx0, 0.f);
        z3_1  = fmaxf(fmaf(ts, Pb1, z3_1)  - tspmx1, 0.f);
        nz4_0 = fminf(fmaf(ts, Pb0, nz4_0) - tspmn0, 0.f);
        nz4_1 = fminf(fmaf(ts, Pb1, nz4_1) - tspmn1, 0.f);

        // ---- half-uniform z rows (need the completed 32-lane sums) ----
        sP  += wP;
        sRu += wRu;
        sRd += wRd;
        z0  = fmaf(ts, sP, z0) - tsf;
        zru = fmaxf(fmaf(-ts, sRu, zru + tsreq), 0.f);
        zrd = fmaxf(fmaf(-ts, sRd, zrd + tsreq), 0.f);
    }

    const float cost0 = bj0 * P0 + cj0;
    const float cost1 = bj1 * P1 + cj1;
    {
        const int bgt = b * (G * T) + t;
        const int i0 = bgt + g0 * T;
        out[i0]              = P0;
        out[SZ + i0]         = Ru0;
        out[2 * SZ + i0]     = Rd0;
        out[3 * SZ + B + i0] = cost0;
        if (v1) {
            const int i1 = bgt + g1 * T;
            out[i1]              = P1;
            out[SZ + i1]         = Ru1;
            out[2 * SZ + i1]     = Rd1;
            out[3 * SZ + B + i1] = cost1;
        }
    }

    if (ws_partial) {
        // per-(b,t) objective partial: sum_g cost + 0.05*b*Ru + 0.02*b*Rd
        float lo = cost0 + 0.05f * bj0 * Ru0 + 0.02f * bj0 * Rd0
                 + (v1 ? (cost1 + 0.05f * bj1 * Ru1 + 0.02f * bj1 * Rd1) : 0.f);
        float s = row_sum1(lo);
        s += swz_xor16(s);
        if (lh == 0) ws_partial[lp] = s;
    }
}

// obj[b] = sum_t ws_partial[b*T + t]   (deterministic, tiny)
__global__ __launch_bounds__(64)
void obj_final_kernel(const float* __restrict__ ws_partial, float* __restrict__ out)
{
    const int b = blockIdx.x * 64 + threadIdx.x;
    if (b < B) {
        float s = 0.f;
        #pragma unroll
        for (int t = 0; t < T; ++t) s += ws_partial[b * T + t];
        out[3 * SZ + b] = s;
    }
}

// Fallback (ws too small): recompute obj from outputs, one block per b
__global__ __launch_bounds__(256)
void obj_kernel(const float* __restrict__ bcost, float* __restrict__ out)
{
    const int b = blockIdx.x;
    const float* Ru = out + SZ     + (size_t)b * (G * T);
    const float* Rd = out + 2 * SZ + (size_t)b * (G * T);
    const float* C  = out + 3 * SZ + B + (size_t)b * (G * T);

    float s = 0.f;
    for (int i = threadIdx.x; i < G * T; i += 256) {
        const int g = i / T;
        const float bg = bcost[g];
        s += C[i] + 0.05f * bg * Ru[i] + 0.02f * bg * Rd[i];
    }
    s = row_sum1(s);
    s += swz_xor16(s);
    __shared__ float sm[8];
    if ((threadIdx.x & 31) == 0) sm[threadIdx.x >> 5] = s;
    __syncthreads();
    if (threadIdx.x == 0) {
        float tot = 0.f;
        #pragma unroll
        for (int i = 0; i < 8; ++i) tot += sm[i];
        out[3 * SZ + b] = tot;
    }
}

extern "C" void kernel_launch(void* const* d_in, const int* in_sizes, int n_in,
                              void* d_out, int out_size, void* d_ws, size_t ws_size,
                              hipStream_t stream) {
    const float* forecast = (const float*)d_in[0];
    const float* pmin_p   = (const float*)d_in[1];
    const float* pmax_p   = (const float*)d_in[2];
    const float* b_p      = (const float*)d_in[3];
    const float* c_p      = (const float*)d_in[4];
    const int*   niter_p  = (const int*)  d_in[5];
    float* out = (float*)d_out;

    // ||K||_2 analytic for this fixed 0/±1 structure (G=50):
    // K^T K = [[4I+J, I, -I],[I, I+J, 0],[-I, 0, I+J]]; largest eig on the
    // ones-subspace is (105+sqrt(17))/2  ->  L = sqrt((105+sqrt(17))/2)
    const double L = sqrt((105.0 + sqrt(17.0)) * 0.5);
    const float tau = (float)(0.9 / L);   // sigma == tau

    const bool use_ws = (ws_size >= (size_t)NLP * sizeof(float));
    float* wsp = use_ws ? (float*)d_ws : nullptr;

    pdhg_lp_kernel<<<NLP / 2, 64, 0, stream>>>(forecast, pmin_p, pmax_p,
                                               b_p, c_p, niter_p, out, wsp, tau);
    if (use_ws) {
        obj_final_kernel<<<(B + 63) / 64, 64, 0, stream>>>(wsp, out);
    } else {
        obj_kernel<<<B, 256, 0, stream>>>(b_p, out);
    }
}